// Round 12
// baseline (163.300 us; speedup 1.0000x reference)
//
#include <hip/hip_runtime.h>
#include <math.h>

#define DEVI __device__ __forceinline__

constexpr int B = 2, P = 16, G = 128, E = 96, N = 128, CO = 2;

DEVI float lrelu(float x) { return x > 0.f ? x : 0.01f * x; }

// ---- workspace layout (floats) ----
constexpr int OFF_MP110  = 0;                        // 32768 (== me011)
constexpr int OFF_MGP    = OFF_MP110 + 32768;        // 8192  mg110 raw halves
constexpr int OFF_S1P    = OFF_MGP + 8192;           // 49152 s001a raw halves
constexpr int OFF_RMP    = OFF_S1P + 49152;          // 1024
constexpr int OFF_RMG    = OFF_RMP + 1024;           // 128
constexpr int OFF_RME    = OFF_RMG + 128;            // 512
constexpr int OFF_RMG011 = OFF_RME + 512;            // 384
constexpr int OFF_WT     = OFF_RMG011 + 384;         // 81920
constexpr int OFF_CPG    = OFF_WT + 81920;           // 4096
constexpr int OFF_EGG    = OFF_CPG + 4096;           // 24576
constexpr int OFF_BFG    = OFF_EGG + 24576;          // 32768
constexpr int OFF_M110G  = OFF_BFG + 32768;          // 4096
constexpr int OFF_M011EG = OFF_M110G + 4096;         // 24576
constexpr int OFF_S001BG = OFF_M011EG + 24576;       // 24576
constexpr int OFF_PARTS  = OFF_S001BG + 24576;       // 2*4*64*6656 = 3407872
// partials[b][nc][gc64][6656]: [0:512)=m110(nn*16+p), [512:3584)=psum, [3584:6656)=pmax

// ---------------------------------------------------------------------------
// K0: tiny input reductions + W1 transpose/fold. 64 blocks. [R11-proven]
__global__ void __launch_bounds__(256) k_prep(
    const float* __restrict__ x110, const float* __restrict__ x011,
    const float* __restrict__ W1,
    float* __restrict__ rmpG, float* __restrict__ rmgG,
    float* __restrict__ rmeG, float* __restrict__ rmg011G,
    float* __restrict__ wT) {
  const int blk = blockIdx.x, tid = threadIdx.x;
  if (blk < 56) {
    for (int idx = blk * 256 + tid; idx < 81920; idx += 56 * 256) {
      int m = idx >> 14, r = idx & 16383;
      int c = r >> 7, nn = r & 127;
      float v;
      if (m == 0)      v = W1[nn * 128 + c];
      else if (m == 1) v = W1[16384 + nn * 128 + c] + W1[5 * 16384 + nn * 128 + c];
      else if (m == 2) v = W1[2 * 16384 + nn * 128 + c];
      else if (m == 3) v = W1[3 * 16384 + nn * 128 + c];
      else             v = W1[4 * 16384 + nn * 128 + c] + W1[6 * 16384 + nn * 128 + c];
      wT[idx] = v;
    }
  } else {
    int t = (blk - 56) * 256 + tid;
    if (t < 1024) {
      int g = t & 127, c = (t >> 7) & 3, b = t >> 9;
      const float* base = x110 + ((b * 4 + c) * P) * G + g;
      float m = -INFINITY;
      for (int p = 0; p < P; p++) m = fmaxf(m, base[p * G]);
      rmpG[t] = m;
    } else if (t < 1152) {
      int i = t - 1024;
      int p = i & 15, c = (i >> 4) & 3, b = i >> 6;
      const float* base = x110 + ((b * 4 + c) * P + p) * G;
      float m = -INFINITY;
      for (int g = 0; g < G; g++) m = fmaxf(m, base[g]);
      rmgG[i] = m;
    } else if (t < 1664) {
      int i = t - 1152;
      int g = i & 127, c = (i >> 7) & 1, b = i >> 8;
      const float* base = x011 + ((size_t)(b * 2 + c) * G + g) * E;
      float m = -INFINITY;
      for (int e = 0; e < E; e++) m = fmaxf(m, base[e]);
      rmeG[i] = m;
    } else if (t < 2048) {
      int i = t - 1664;
      int e = i % 96; int r = i / 96; int c = r & 1, b = r >> 1;
      const float* base = x011 + ((size_t)(b * 2 + c) * G) * E + e;
      float m = -INFINITY;
      for (int g = 0; g < G; g++) m = fmaxf(m, base[g * E]);
      rmg011G[i] = m;
    }
  }
}

// ---------------------------------------------------------------------------
// K1: layer 0, one block per (b,n,g-half). 512 blocks. [R11-proven verbatim]
__global__ void __launch_bounds__(256) k_layer0(
    const float* __restrict__ x110, const float* __restrict__ x011,
    const float* __restrict__ x001,
    const float* __restrict__ W0_110, const float* __restrict__ b0_110,
    const float* __restrict__ W0_011, const float* __restrict__ b0_011,
    const float* __restrict__ W0_001, const float* __restrict__ b0_001,
    const float* __restrict__ rmpG, const float* __restrict__ rmgG,
    const float* __restrict__ rmeG, const float* __restrict__ rmg011G,
    float* __restrict__ mp110, float* __restrict__ mgp,
    float* __restrict__ s1p) {
  __shared__ float xs[4 * 16 * 64];
  __shared__ float v0h[64 * 97];
  __shared__ float u0h[16 * 64];
  __shared__ float rmpL[256], rmeL[128], rmgSL[64], rmg011L[192], x001L[96];
  __shared__ float mpu[64], mev[64], part[256];
  const int blk = blockIdx.x;
  const int b = blk >> 8, n = (blk >> 1) & 127, gh = blk & 1;
  const int bn = b * 128 + n, g0 = gh * 64;
  const int tid = threadIdx.x;

#pragma unroll
  for (int k = 0; k < 4; k++) {
    int i4 = tid + k * 256;
    int g4 = i4 & 15, p = (i4 >> 4) & 15, cc = i4 >> 8;
    *(float4*)&xs[(cc * 16 + p) * 64 + g4 * 4] =
        *(const float4*)(x110 + ((size_t)(b * 4 + cc) * 16 + p) * 128 + g0 + g4 * 4);
  }
  {
    int cc = tid >> 6, gp = tid & 63;
    rmpL[tid] = rmpG[b * 512 + cc * 128 + g0 + gp];
  }
  if (tid < 128) {
    int c2 = tid >> 6, gp = tid & 63;
    rmeL[tid] = rmeG[b * 256 + c2 * 128 + g0 + gp];
  }
  if (tid < 64) rmgSL[tid] = rmgG[b * 64 + tid];
  if (tid < 192) rmg011L[tid] = rmg011G[b * 192 + tid];
  if (tid < 96) x001L[tid] = x001[b * 96 + tid];
  __syncthreads();

  float w0[4], w1[4], w2[4];
#pragma unroll
  for (int cc = 0; cc < 4; cc++) {
    w0[cc] = W0_110[n * 4 + cc];
    w1[cc] = W0_110[512 + n * 4 + cc];
    w2[cc] = W0_110[1024 + n * 4 + cc];
  }
  float we0 = W0_011[512 + n * 2], we1 = W0_011[512 + n * 2 + 1];
  float bu = b0_110[n] + b0_110[128 + n] + b0_110[256 + n] + b0_011[256 + n];
  float vw00 = W0_011[n * 2], vw01 = W0_011[n * 2 + 1];
  float vw10 = W0_011[256 + n * 2], vw11 = W0_011[256 + n * 2 + 1];
  float w001 = W0_001[n];
  float bv = b0_011[n] + b0_011[128 + n] + b0_001[n];

#pragma unroll
  for (int k = 0; k < 4; k++) {
    int i = tid + k * 256, p = i >> 6, gp = i & 63;
    float acc = bu + we0 * rmeL[gp] + we1 * rmeL[64 + gp];
#pragma unroll
    for (int cc = 0; cc < 4; cc++)
      acc += w0[cc] * xs[(cc * 16 + p) * 64 + gp] + w1[cc] * rmpL[cc * 64 + gp]
           + w2[cc] * rmgSL[cc * 16 + p];
    u0h[i] = acc;
  }
  {
    const float* xa = x011 + (size_t)(b * 2) * 12288;
    const float* xb = xa + 12288;
#pragma unroll
    for (int k = 0; k < 24; k++) {
      int i = tid + k * 256;
      int gp = i / 96, e = i - gp * 96;
      int g = g0 + gp;
      float val = bv + vw00 * xa[g * 96 + e] + vw01 * xb[g * 96 + e]
                + vw10 * rmg011L[e] + vw11 * rmg011L[96 + e] + w001 * x001L[e];
      v0h[gp * 97 + e] = val;
    }
  }
  __syncthreads();
  {
    int gp = tid & 63, q = tid >> 6;
    const float* r = &v0h[gp * 97 + q * 24];
    float m = -INFINITY;
    for (int j = 0; j < 24; j++) m = fmaxf(m, r[j]);
    part[q * 64 + gp] = m;
  }
  if (tid < 64) {
    float m = -INFINITY;
    for (int p = 0; p < P; p++) m = fmaxf(m, u0h[p * 64 + tid]);
    mpu[tid] = m;
  }
  __syncthreads();
  if (tid < 64) {
    float m = fmaxf(fmaxf(part[tid], part[64 + tid]),
                    fmaxf(part[128 + tid], part[192 + tid]));
    mev[tid] = m;
    mp110[bn * 128 + g0 + tid] = lrelu(mpu[tid] + m);
  }
  __syncthreads();
  {
    int p = tid >> 4, ch = tid & 15;
    float m = -INFINITY;
    for (int gp = ch * 4; gp < ch * 4 + 4; gp++)
      m = fmaxf(m, u0h[p * 64 + gp] + mev[gp]);
    part[tid] = m;
  }
  __syncthreads();
  if (tid < 16) {
    float m = -INFINITY;
    for (int ch = 0; ch < 16; ch++) m = fmaxf(m, part[tid * 16 + ch]);
    mgp[(bn * 2 + gh) * 16 + tid] = m;
  }
  if (tid < 96) {
    float m = -INFINITY;
    for (int gp = 0; gp < 64; gp++)
      m = fmaxf(m, mpu[gp] + v0h[gp * 97 + tid]);
    s1p[(bn * 2 + gh) * 96 + tid] = m;
  }
}

// ---------------------------------------------------------------------------
// K2: g-independent bias GEMMs (cp/eg/bf), half-folds inline. 240 blocks.
__global__ void k_sg2(const float* __restrict__ wT, const float* __restrict__ mgp,
                      const float* __restrict__ s1p, const float* __restrict__ mp110,
                      float* __restrict__ cpG, float* __restrict__ egG,
                      float* __restrict__ bfG) {
  const float* w15T = wT + 16384;
  const float* w2T  = wT + 2 * 16384;
  const float* w46T = wT + 4 * 16384;
  int t = blockIdx.x * 256 + threadIdx.x;
  if (t < 4096) {                      // cpG[b,n,p] = sum_c w2T * mg110
    int p = t & 15, n = (t >> 4) & 127, b = t >> 11;
    float acc = 0.f;
    for (int c = 0; c < N; c++) {
      float m = fmaxf(mgp[(b * 128 + c) * 32 + p], mgp[(b * 128 + c) * 32 + 16 + p]);
      acc += w2T[c * 128 + n] * lrelu(m);
    }
    cpG[t] = acc;
  } else if (t < 36864) {              // bfG[b,n,g] = sum_c w15T * mp110
    int i = t - 4096;
    int g = i & 127, n = (i >> 7) & 127, b = i >> 14;
    float acc = 0.f;
    for (int c = 0; c < N; c++)
      acc += w15T[c * 128 + n] * mp110[(b * 128 + c) * 128 + g];
    bfG[(b * 128 + n) * 128 + g] = acc;
  } else if (t < 61440) {              // egG[b,n,e] = sum_c w46T * s001a
    int i = t - 36864;
    int e = i % 96; int r = i / 96; int n = r & 127, b = r >> 7;
    float acc = 0.f;
    for (int c = 0; c < N; c++) {
      float m = fmaxf(s1p[(b * 128 + c) * 192 + e], s1p[(b * 128 + c) * 192 + 96 + e]);
      acc += w46T[c * 128 + n] * lrelu(m);
    }
    egG[(b * 128 + n) * 96 + e] = acc;
  }
}

// ---------------------------------------------------------------------------
// K3: FUSED layer-1 GEMM + g-reduction. Block = (b, gc of 2 g, nc of 32 n).
// 512 blocks, 256 threads. No U1/V1 materialization.
__global__ void __launch_bounds__(256) k_fused(
    const float* __restrict__ x110, const float* __restrict__ x011,
    const float* __restrict__ x001,
    const float* __restrict__ W0_110, const float* __restrict__ b0_110,
    const float* __restrict__ W0_011, const float* __restrict__ b0_011,
    const float* __restrict__ W0_001, const float* __restrict__ b0_001,
    const float* __restrict__ rmpG, const float* __restrict__ rmgG,
    const float* __restrict__ rmeG, const float* __restrict__ rmg011G,
    const float* __restrict__ wT, const float* __restrict__ cpG,
    const float* __restrict__ egG, const float* __restrict__ bfG,
    const float* __restrict__ b1, float* __restrict__ partials) {
  __shared__ float s110c[128 * 16];        // raw U0 then s110
  __shared__ float s011c[128 * 96];        // raw V0 then s011
  __shared__ float W0L110[1536], W0L011[768], W0L001[128];
  __shared__ float busum[128], bvsum[128], mpu[128], mev[128];
  __shared__ float x011row[192], rmg011s[192], x001s[96];
  __shared__ float x110col[64], rmg110p[64], rmp4[4], rme2[2];
  __shared__ float partM[256], redV[256], redU[256];
  const int blk = blockIdx.x;
  const int b = blk >> 8, rr = blk & 255, gc = rr >> 2, nc = rr & 3;
  const int n0 = nc * 32;
  const int tid = threadIdx.x;
  const int nn = tid >> 3, lane8 = tid & 7;
  const int n = n0 + nn, e0 = lane8 * 12, p2 = lane8 * 2;

  for (int i = tid; i < 1536; i += 256) W0L110[i] = W0_110[i];
  for (int i = tid; i < 768; i += 256) W0L011[i] = W0_011[i];
  if (tid < 128) {
    W0L001[tid] = W0_001[tid];
    busum[tid] = b0_110[tid] + b0_110[128 + tid] + b0_110[256 + tid]
               + b0_011[256 + tid];
    bvsum[tid] = b0_011[tid] + b0_011[128 + tid] + b0_001[tid];
  }
  if (tid < 192) rmg011s[tid] = rmg011G[b * 192 + tid];
  if (tid < 96) x001s[tid] = x001[b * 96 + tid];
  if (tid < 64) rmg110p[tid] = rmgG[b * 64 + tid];

  const float bb = b1[n] + b1[128 + n] + b1[256 + n] + b1[640 + n];
  const float bv = b1[384 + n] + b1[512 + n] + b1[768 + n];
  float cpr[2];
  cpr[0] = cpG[(b * 128 + n) * 16 + p2];
  cpr[1] = cpG[(b * 128 + n) * 16 + p2 + 1];
  float egr[12];
#pragma unroll
  for (int j = 0; j < 12; j++) egr[j] = egG[(b * 128 + n) * 96 + e0 + j];

  float psum[12], pmax[12], macc0 = 0.f, macc1 = 0.f;
#pragma unroll
  for (int j = 0; j < 12; j++) { psum[j] = 0.f; pmax[j] = -INFINITY; }

  const float* w0T = wT;
  const float* w3T = wT + 3 * 16384;

  for (int gi = 0; gi < 2; gi++) {
    const int g = gc * 2 + gi;
    // stage g-locals
    if (tid < 192) {
      int c = tid / 96, e = tid % 96;
      x011row[tid] = x011[((size_t)(b * 2 + c) * 128 + g) * 96 + e];
    }
    if (tid < 64) {
      int c = tid >> 4, p = tid & 15;
      x110col[tid] = x110[((size_t)(b * 4 + c) * 16 + p) * 128 + g];
    }
    if (tid < 4) rmp4[tid] = rmpG[(b * 4 + tid) * 128 + g];
    if (tid < 2) rme2[tid] = rmeG[(b * 2 + tid) * 128 + g];
    __syncthreads();
    // raw U0 column (c,p)   [R11-proven formulas]
#pragma unroll
    for (int k = 0; k < 8; k++) {
      int i = tid + k * 256, c = i >> 4, p = i & 15;
      float acc = busum[c] + W0L011[512 + c * 2] * rme2[0]
                + W0L011[512 + c * 2 + 1] * rme2[1];
#pragma unroll
      for (int cc = 0; cc < 4; cc++)
        acc += W0L110[c * 4 + cc] * x110col[cc * 16 + p]
             + W0L110[512 + c * 4 + cc] * rmp4[cc]
             + W0L110[1024 + c * 4 + cc] * rmg110p[cc * 16 + p];
      s110c[i] = acc;
    }
    // raw V0 column (c,e)
    for (int k = 0; k < 48; k++) {
      int i = tid + k * 256;
      int c = i / 96, e = i - c * 96;
      float v = bvsum[c]
              + W0L011[c * 2] * x011row[e] + W0L011[c * 2 + 1] * x011row[96 + e]
              + W0L011[256 + c * 2] * rmg011s[e]
              + W0L011[256 + c * 2 + 1] * rmg011s[96 + e]
              + W0L001[c] * x001s[e];
      s011c[i] = v;
    }
    __syncthreads();
    if (tid < 128) {
      float m = -INFINITY;
      for (int p = 0; p < P; p++) m = fmaxf(m, s110c[tid * 16 + p]);
      mpu[tid] = m;
    }
    {
      int c = tid >> 1, h = tid & 1;
      const float* r = &s011c[c * 96 + h * 48];
      float m = -INFINITY;
      for (int j = 0; j < 48; j++) m = fmaxf(m, r[j]);
      partM[tid] = m;
    }
    __syncthreads();
    if (tid < 128) mev[tid] = fmaxf(partM[tid * 2], partM[tid * 2 + 1]);
    __syncthreads();
#pragma unroll
    for (int k = 0; k < 8; k++) {
      int i = tid + k * 256, c = i >> 4;
      s110c[i] = lrelu(s110c[i] + mev[c]);
    }
    for (int k = 0; k < 48; k++) {
      int i = tid + k * 256, c = i / 96;
      s011c[i] = lrelu(s011c[i] + mpu[c]);
    }
    __syncthreads();
    // GEMM: 1n x 12e (V) + 1n x 2p (U), K=128
    float4 a0 = make_float4(0.f, 0.f, 0.f, 0.f);
    float4 a1 = a0, a2 = a0;
    float u0 = 0.f, u1 = 0.f;
    for (int c = 0; c < 128; c++) {
      float w3 = w3T[c * 128 + n];
      float w0v = w0T[c * 128 + n];
      float4 s0 = *(const float4*)&s011c[c * 96 + e0];
      float4 s1 = *(const float4*)&s011c[c * 96 + e0 + 4];
      float4 s2 = *(const float4*)&s011c[c * 96 + e0 + 8];
      a0.x += w3 * s0.x; a0.y += w3 * s0.y; a0.z += w3 * s0.z; a0.w += w3 * s0.w;
      a1.x += w3 * s1.x; a1.y += w3 * s1.y; a1.z += w3 * s1.z; a1.w += w3 * s1.w;
      a2.x += w3 * s2.x; a2.y += w3 * s2.y; a2.z += w3 * s2.z; a2.w += w3 * s2.w;
      float2 sp = *(const float2*)&s110c[c * 16 + p2];
      u0 += w0v * sp.x; u1 += w0v * sp.y;
    }
    float vp[12];
    vp[0] = a0.x + bv + egr[0]; vp[1] = a0.y + bv + egr[1];
    vp[2] = a0.z + bv + egr[2]; vp[3] = a0.w + bv + egr[3];
    vp[4] = a1.x + bv + egr[4]; vp[5] = a1.y + bv + egr[5];
    vp[6] = a1.z + bv + egr[6]; vp[7] = a1.w + bv + egr[7];
    vp[8] = a2.x + bv + egr[8]; vp[9] = a2.y + bv + egr[9];
    vp[10] = a2.z + bv + egr[10]; vp[11] = a2.w + bv + egr[11];
    float bfg = bfG[(b * 128 + n) * 128 + g];
    float up0 = u0 + bb + cpr[0] + bfg;
    float up1 = u1 + bb + cpr[1] + bfg;
    float vmax = -INFINITY;
#pragma unroll
    for (int j = 0; j < 12; j++) vmax = fmaxf(vmax, vp[j]);
    redV[tid] = vmax;
    redU[tid] = fmaxf(up0, up1);
    __syncthreads();
    float mxe = -INFINITY, mxp = -INFINITY;
#pragma unroll
    for (int t8 = 0; t8 < 8; t8++) {
      mxe = fmaxf(mxe, redV[nn * 8 + t8]);
      mxp = fmaxf(mxp, redU[nn * 8 + t8]);
    }
    macc0 += lrelu(up0 + mxe);
    macc1 += lrelu(up1 + mxe);
#pragma unroll
    for (int j = 0; j < 12; j++) {
      float pre = mxp + vp[j];
      psum[j] += lrelu(pre);
      pmax[j] = fmaxf(pmax[j], pre);
    }
    __syncthreads();   // protects redV/redU + s-arrays before next gi
  }
  // write partials
  float* pb = partials + ((size_t)((b * 4 + nc) * 64 + gc)) * 6656;
  pb[nn * 16 + p2] = macc0;
  pb[nn * 16 + p2 + 1] = macc1;
  float* ps = pb + 512 + nn * 96 + e0;
  float* pm = pb + 3584 + nn * 96 + e0;
#pragma unroll
  for (int k = 0; k < 3; k++) {
    *(float4*)(ps + k * 4) = make_float4(psum[k * 4], psum[k * 4 + 1],
                                         psum[k * 4 + 2], psum[k * 4 + 3]);
    *(float4*)(pm + k * 4) = make_float4(pmax[k * 4], pmax[k * 4 + 1],
                                         pmax[k * 4 + 2], pmax[k * 4 + 3]);
  }
}

// ---------------------------------------------------------------------------
// K4: fold partials over 64 g-chunks. grid = (b, nc, 13 chunks) = 104 blocks.
__global__ void __launch_bounds__(256) k_combine(
    const float* __restrict__ partials,
    float* __restrict__ m110G, float* __restrict__ m011eG,
    float* __restrict__ s001bG) {
  const int blk = blockIdx.x;
  const int b = blk / 52, r = blk % 52, nc = r / 13, chunk = r % 13;
  const int tid = threadIdx.x;
#pragma unroll
  for (int it = 0; it < 2; it++) {
    int item = chunk * 512 + it * 256 + tid;
    const float* base = partials + ((size_t)(b * 4 + nc) * 64) * 6656 + item;
    if (item < 512) {
      float a = 0.f;
      for (int gcc = 0; gcc < 64; gcc++) a += base[(size_t)gcc * 6656];
      int nn = item >> 4, p = item & 15;
      m110G[(b * 128 + nc * 32 + nn) * 16 + p] = a * (1.f / G);
    } else if (item < 3584) {
      float a = 0.f;
      for (int gcc = 0; gcc < 64; gcc++) a += base[(size_t)gcc * 6656];
      int r2 = item - 512;
      int nn = r2 / 96, e = r2 % 96;
      m011eG[(b * 128 + nc * 32 + nn) * 96 + e] = a * (1.f / G);
    } else {
      float m = -INFINITY;
      for (int gcc = 0; gcc < 64; gcc++) m = fmaxf(m, base[(size_t)gcc * 6656]);
      int r2 = item - 3584;
      int nn = r2 / 96, e = r2 % 96;
      s001bG[(b * 128 + nc * 32 + nn) * 96 + e] = lrelu(m);
    }
  }
}

// ---------------------------------------------------------------------------
// K5: heads, LDS-staged. One block per (b,o), 128 thr. [R8-proven verbatim]
__global__ void __launch_bounds__(128) k_final(const float* __restrict__ m110,
                                               const float* __restrict__ m011e,
                                               const float* __restrict__ s001,
                                               const float* __restrict__ Wact,
                                               const float* __restrict__ bact,
                                               const float* __restrict__ Wcrit,
                                               const float* __restrict__ bcrit,
                                               float* __restrict__ out) {
  __shared__ float buf[128][97];
  __shared__ float m110s[128][17];
  __shared__ float sm011[N], sm001[N], sce1[E], sce[E], scp[P], srow[P], scol[E];
  const int bo = blockIdx.x;
  const int o = bo & 1, b = bo >> 1;
  const int t = threadIdx.x;

#pragma unroll
  for (int k = 0; k < 16; k++) {
    int i = t + k * 128;
    m110s[i >> 4][i & 15] = m110[b * 2048 + i];
  }
  for (int k = 0; k < 96; k++) {
    int i = t + k * 128;
    buf[i / 96][i % 96] = m011e[b * 12288 + i];
  }
  __syncthreads();
  {
    float s = 0.f;
    for (int e = 0; e < E; e++) s += buf[t][e];
    sm011[t] = s * (1.f / E);
  }
  if (t < 96) {
    const float* wc1 = Wcrit + (1 * CO + o) * N;
    float c = 0.f;
    for (int n = 0; n < N; n++) c += wc1[n] * buf[n][t];
    sce1[t] = c;
  }
  __syncthreads();
  for (int k = 0; k < 96; k++) {
    int i = t + k * 128;
    buf[i / 96][i % 96] = s001[b * 12288 + i];
  }
  __syncthreads();
  {
    float s = 0.f;
    for (int e = 0; e < E; e++) s += buf[t][e];
    sm001[t] = s * (1.f / E);
  }
  if (t < 96) {
    const float* wc2 = Wcrit + (2 * CO + o) * N;
    float c = 0.f;
    for (int n = 0; n < N; n++) c += wc2[n] * buf[n][t];
    sce[t] = sce1[t] + c + bcrit[CO + o] + bcrit[2 * CO + o];
  }
  __syncthreads();
  if (t < P) {
    const float* wa0 = Wact + o * N;
    const float* wa1 = Wact + (1 * CO + o) * N;
    const float* wa2 = Wact + (2 * CO + o) * N;
    const float* wc0 = Wcrit + o * N;
    float a = 0.f, c = 0.f, aa = 0.f;
    for (int n = 0; n < N; n++) {
      float m = m110s[n][t];
      a += wa0[n] * m;
      c += wc0[n] * m;
      aa += wa1[n] * sm011[n] + wa2[n] * sm001[n];
    }
    float act = a + aa + bact[o] + bact[CO + o] + bact[2 * CO + o];
    out[(b * CO + o) * P + t] = lrelu(act);
    scp[t] = c + bcrit[o];
  }
  __syncthreads();
  if (t < P) {
    float m = -INFINITY;
    for (int e = 0; e < E; e++) m = fmaxf(m, lrelu(scp[t] + sce[e]));
    srow[t] = m;
  } else if (t < P + E) {
    int e = t - P;
    float m = -INFINITY;
    for (int p = 0; p < P; p++) m = fmaxf(m, lrelu(scp[p] + sce[e]));
    scol[e] = m;
  }
  __syncthreads();
  if (t == 0) {
    float v110 = 0.f, v011 = 0.f;
    for (int p = 0; p < P; p++) v110 += srow[p];
    for (int e = 0; e < E; e++) v011 += scol[e];
    out[B * CO * P + b * CO + o] = 2.f + v110 + 2.f * v011;
  }
}

extern "C" void kernel_launch(void* const* d_in, const int* in_sizes, int n_in,
                              void* d_out, int out_size, void* d_ws, size_t ws_size,
                              hipStream_t stream) {
  const float* x110   = (const float*)d_in[0];
  const float* x011   = (const float*)d_in[1];
  const float* x001   = (const float*)d_in[2];
  const float* W0_110 = (const float*)d_in[3];
  const float* b0_110 = (const float*)d_in[4];
  const float* W0_011 = (const float*)d_in[5];
  const float* b0_011 = (const float*)d_in[6];
  const float* W0_001 = (const float*)d_in[7];
  const float* b0_001 = (const float*)d_in[8];
  const float* W1     = (const float*)d_in[9];
  const float* b1     = (const float*)d_in[10];
  const float* Wact   = (const float*)d_in[11];
  const float* bact   = (const float*)d_in[12];
  const float* Wcrit  = (const float*)d_in[13];
  const float* bcrit  = (const float*)d_in[14];
  float* out = (float*)d_out;
  float* w = (float*)d_ws;

  float* mp110  = w + OFF_MP110;
  float* mgp    = w + OFF_MGP;
  float* s1p    = w + OFF_S1P;
  float* rmpG   = w + OFF_RMP;
  float* rmgG   = w + OFF_RMG;
  float* rmeG   = w + OFF_RME;
  float* rmg011 = w + OFF_RMG011;
  float* wT     = w + OFF_WT;
  float* cpG    = w + OFF_CPG;
  float* egG    = w + OFF_EGG;
  float* bfG    = w + OFF_BFG;
  float* m110G  = w + OFF_M110G;
  float* m011eG = w + OFF_M011EG;
  float* s001bG = w + OFF_S001BG;
  float* partB  = w + OFF_PARTS;

  k_prep<<<64, 256, 0, stream>>>(x110, x011, W1, rmpG, rmgG, rmeG, rmg011, wT);
  k_layer0<<<512, 256, 0, stream>>>(x110, x011, x001, W0_110, b0_110, W0_011,
                                    b0_011, W0_001, b0_001,
                                    rmpG, rmgG, rmeG, rmg011, mp110, mgp, s1p);
  k_sg2<<<240, 256, 0, stream>>>(wT, mgp, s1p, mp110, cpG, egG, bfG);
  k_fused<<<512, 256, 0, stream>>>(x110, x011, x001, W0_110, b0_110, W0_011,
                                   b0_011, W0_001, b0_001,
                                   rmpG, rmgG, rmeG, rmg011, wT, cpG, egG, bfG,
                                   b1, partB);
  k_combine<<<104, 256, 0, stream>>>(partB, m110G, m011eG, s001bG);
  k_final<<<4, 128, 0, stream>>>(m110G, m011eG, s001bG, Wact, bact,
                                 Wcrit, bcrit, out);
}